// Round 2
// baseline (612.768 us; speedup 1.0000x reference)
//
#include <hip/hip_runtime.h>

typedef unsigned short u16;
typedef float f32x4 __attribute__((ext_vector_type(4)));
typedef __bf16 bf16x8 __attribute__((ext_vector_type(8)));

// ---------- bf16 helpers (RNE) ----------
__device__ __forceinline__ u16 f2bf(float f) {
    unsigned u = __float_as_uint(f);
    u += 0x7FFFu + ((u >> 16) & 1u);
    return (u16)(u >> 16);
}
__device__ __forceinline__ float b2f(u16 h) {
    return __uint_as_float(((unsigned)h) << 16);
}

// ---------- async global->LDS, 16B per lane, wave-uniform LDS base ----------
__device__ __forceinline__ void async16(const u16* g, u16* l) {
    __builtin_amdgcn_global_load_lds(
        (__attribute__((address_space(1))) void*)(u16*)g,
        (__attribute__((address_space(3))) void*)l,
        16, 0, 0);
}

#define T_TOK 4096
#define DIM   2048

// ---------- weight fp32 -> bf16 cast, vectorized ----------
__global__ __launch_bounds__(256) void castw_kernel(const float* __restrict__ src,
                                                    u16* __restrict__ dst, int n4) {
    int i = blockIdx.x * 256 + threadIdx.x;
    if (i < n4) {
        float4 f = ((const float4*)src)[i];
        ushort4 u;
        u.x = f2bf(f.x); u.y = f2bf(f.y); u.z = f2bf(f.z); u.w = f2bf(f.w);
        ((ushort4*)dst)[i] = u;
    }
}

// ---------- LayerNorm + bf16 cast; one block per token ----------
__global__ __launch_bounds__(256) void ln_cast_kernel(const float* __restrict__ x,
                                                      const float* __restrict__ g,
                                                      const float* __restrict__ b,
                                                      u16* __restrict__ o) {
    __shared__ float s1[4], s2[4];
    int t = blockIdx.x, tid = threadIdx.x;
    int wave = tid >> 6, lane = tid & 63;
    size_t base = (size_t)t * DIM;
    float v[8];
    float s = 0.f;
#pragma unroll
    for (int j = 0; j < 8; ++j) { v[j] = x[base + j * 256 + tid]; s += v[j]; }
#pragma unroll
    for (int o2 = 32; o2; o2 >>= 1) s += __shfl_xor(s, o2);
    if (lane == 0) s1[wave] = s;
    __syncthreads();
    float mu = (s1[0] + s1[1] + s1[2] + s1[3]) * (1.f / DIM);
    float q = 0.f;
#pragma unroll
    for (int j = 0; j < 8; ++j) { float d = v[j] - mu; q += d * d; }
#pragma unroll
    for (int o2 = 32; o2; o2 >>= 1) q += __shfl_xor(q, o2);
    if (lane == 0) s2[wave] = q;
    __syncthreads();
    float var = (s2[0] + s2[1] + s2[2] + s2[3]) * (1.f / DIM);
    float rs = rsqrtf(var + 1e-5f);
#pragma unroll
    for (int j = 0; j < 8; ++j) {
        int d = j * 256 + tid;
        o[base + d] = f2bf((v[j] - mu) * rs * g[d] + b[d]);
    }
}

// ---------- GEMM: C[m,n] = sum_k A[m,k] * W[n,k]  (both row-major bf16) ----------
// 128x128 tile, BK=32, 256 threads = 4 waves (2x2), each wave 4x4 x mfma 16x16x32.
// LDS 16B-chunk XOR swizzle: slot of chunk c in row R = c ^ ((R>>1)&3) -> each
// 8-lane ds_read_b128 phase covers all 32 banks exactly once (conflict-free).
// EPI: 0 = bias+bf16; 1 = bias+min(softplus,1)+bf16; 2 = bias+resid+f32;
//      3 = split-K partial, atomicAdd fp32 (no bias). blockIdx.z*K = k-slice base.
#define BM 128
#define BN 128
#define BK 32

template <int EPI>
__global__ __launch_bounds__(256) void gemm_bt(const u16* __restrict__ A, int lda,
                                               const u16* __restrict__ W, int ldw,
                                               const float* __restrict__ bias,
                                               const float* __restrict__ resid,
                                               void* __restrict__ C, int ldc, int K) {
    __shared__ __align__(16) u16 lAB[2 * BM * BK];  // 16 KB: [A 128x32 | W 128x32]
    const int tid = threadIdx.x;
    const int wave = tid >> 6, lane = tid & 63;
    const int quad = lane >> 4, l16 = lane & 15;
    const int tM = blockIdx.x * BM;
    const int tN = blockIdx.y * BN;
    const int wr = wave >> 1, wc = wave & 1;

    const int kz = blockIdx.z * K;   // split-K slice base (0 when gridDim.z==1)
    A += kz;
    W += kz;

    // staging: 16 chunks of 1KB; wave w owns chunks w*4..w*4+3. chunks 0-7 = A, 8-15 = W.
    const bool isB = (wave >= 2);
    const u16* src = isB ? W : A;
    const int srcld = isB ? ldw : lda;
    const int rowbase = (isB ? tN : tM) + (wave & 1) * 64 + (lane >> 2);
    const int colofs = ((lane & 3) ^ ((lane >> 3) & 3)) * 8;   // XOR swizzle
    const u16* gptr[4];
    u16* ldst[4];
#pragma unroll
    for (int i = 0; i < 4; ++i) {
        gptr[i] = src + (size_t)(rowbase + i * 16) * srcld + colofs;
        ldst[i] = &lAB[(wave * 4 + i) * 512];
    }

    const u16* lA = lAB;
    const u16* lB = lAB + BM * BK;
    const int sw = (l16 >> 1) & 3;                             // XOR swizzle (read)
    int a_off[4], b_off[4];
#pragma unroll
    for (int i = 0; i < 4; ++i) {
        a_off[i] = (wr * 64 + i * 16 + l16) * BK + ((quad ^ sw) * 8);
        b_off[i] = (wc * 64 + i * 16 + l16) * BK + ((quad ^ sw) * 8);
    }

    f32x4 acc[4][4] = {};

    for (int kt = 0; kt < K; kt += BK) {
#pragma unroll
        for (int i = 0; i < 4; ++i) async16(gptr[i] + kt, ldst[i]);
        __syncthreads();  // drains vmcnt(0) before barrier
        bf16x8 af[4], bfr[4];
#pragma unroll
        for (int i = 0; i < 4; ++i) af[i] = *(const bf16x8*)&lA[a_off[i]];
#pragma unroll
        for (int i = 0; i < 4; ++i) bfr[i] = *(const bf16x8*)&lB[b_off[i]];
#pragma unroll
        for (int mi = 0; mi < 4; ++mi)
#pragma unroll
            for (int ni = 0; ni < 4; ++ni)
                acc[mi][ni] = __builtin_amdgcn_mfma_f32_16x16x32_bf16(
                    af[mi], bfr[ni], acc[mi][ni], 0, 0, 0);
        __syncthreads();
    }

    // epilogue: D row = quad*4+r, col = l16 (within each 16x16)
#pragma unroll
    for (int mi = 0; mi < 4; ++mi) {
#pragma unroll
        for (int ni = 0; ni < 4; ++ni) {
            int col = tN + wc * 64 + ni * 16 + l16;
            float bv = (EPI == 3) ? 0.f : bias[col];
#pragma unroll
            for (int r = 0; r < 4; ++r) {
                int row = tM + wr * 64 + mi * 16 + quad * 4 + r;
                float v = acc[mi][ni][r] + bv;
                size_t idx = (size_t)row * ldc + col;
                if constexpr (EPI == 0) {
                    ((u16*)C)[idx] = f2bf(v);
                } else if constexpr (EPI == 1) {
                    float sp = log1pf(__expf(fminf(v, 20.f)));
                    if (v > 20.f) sp = v;
                    ((u16*)C)[idx] = f2bf(fminf(sp, 1.0f));
                } else if constexpr (EPI == 2) {
                    ((float*)C)[idx] = v + resid[idx];
                } else {
                    atomicAdd(&((float*)C)[idx], v);
                }
            }
        }
    }
}

// ---------- dt epilogue: dtb = min(softplus(acc + b_dt), 1) as bf16 ----------
__global__ __launch_bounds__(256) void dt_epi_kernel(const float* __restrict__ acc,
                                                     const float* __restrict__ bias,
                                                     u16* __restrict__ o) {
    int i = blockIdx.x * 256 + threadIdx.x;   // float4 index; 2048/4=512 per row
    int col4 = (i & 511) * 4;
    float4 a = ((const float4*)acc)[i];
    float vs[4] = {a.x, a.y, a.z, a.w};
    ushort4 r;
    u16* rp = (u16*)&r;
#pragma unroll
    for (int j = 0; j < 4; ++j) {
        float v = vs[j] + bias[col4 + j];
        float sp = (v > 20.f) ? v : log1pf(__expf(v));
        rp[j] = f2bf(fminf(sp, 1.0f));
    }
    ((ushort4*)o)[i] = r;
}

// ---------- out epilogue: out += b_out + residual (in place, fp32) ----------
__global__ __launch_bounds__(256) void out_epi_kernel(float* __restrict__ o,
                                                      const float* __restrict__ bias,
                                                      const float* __restrict__ x) {
    int i = blockIdx.x * 256 + threadIdx.x;
    int col4 = (i & 511) * 4;
    float4 a = ((float4*)o)[i];
    float4 xr = ((const float4*)x)[i];
    a.x += bias[col4 + 0] + xr.x;
    a.y += bias[col4 + 1] + xr.y;
    a.z += bias[col4 + 2] + xr.z;
    a.w += bias[col4 + 3] + xr.w;
    ((float4*)o)[i] = a;
}

// ---------- P[t,n] = (x_ssm . W_B[n] + b_B[n]) * (x_ssm . W_C[n] + b_C[n]) ----------
__global__ __launch_bounds__(256) void bc_kernel(const u16* __restrict__ xz,
                                                 const float* __restrict__ WB,
                                                 const float* __restrict__ WC,
                                                 const float* __restrict__ bB,
                                                 const float* __restrict__ bC,
                                                 float* __restrict__ P) {
    __shared__ float xs[4][DIM];   // 32 KB
    __shared__ float dots[4][32];
    int t0 = blockIdx.x * 4, tid = threadIdx.x;
    int wave = tid >> 6, lane = tid & 63;
    for (int tk = 0; tk < 4; ++tk)
#pragma unroll
        for (int j = 0; j < 8; ++j)
            xs[tk][j * 256 + tid] = b2f(xz[(size_t)(t0 + tk) * 4096 + j * 256 + tid]);
    __syncthreads();
    for (int i = 0; i < 8; ++i) {
        int r = wave * 8 + i;  // 0..31
        const float* wrow = (r < 16) ? (WB + (size_t)r * DIM) : (WC + (size_t)(r - 16) * DIM);
        float w[32];
#pragma unroll
        for (int j = 0; j < 32; ++j) w[j] = wrow[j * 64 + lane];
        for (int tk = 0; tk < 4; ++tk) {
            float p = 0.f;
#pragma unroll
            for (int j = 0; j < 32; ++j) p += w[j] * xs[tk][j * 64 + lane];
#pragma unroll
            for (int o = 32; o; o >>= 1) p += __shfl_xor(p, o);
            if (lane == 0) dots[tk][r] = p;
        }
    }
    __syncthreads();
    if (tid < 64) {
        int tk = tid >> 4, n = tid & 15;
        P[(size_t)(t0 + tk) * 16 + n] =
            (dots[tk][n] + bB[n]) * (dots[tk][n + 16] + bC[n]);
    }
}

// ---------- y = xs * sum_n P[n]*exp(A[n,d]*dt[d]);  gated = y * silu(z) ----------
__global__ __launch_bounds__(256) void ssm_gate_kernel(const u16* __restrict__ dtb,
                                                       const u16* __restrict__ xz,
                                                       const float* __restrict__ A,
                                                       const float* __restrict__ P,
                                                       u16* __restrict__ gated) {
    __shared__ float Pl[16];
    int t = blockIdx.x, tid = threadIdx.x;
    if (tid < 16) Pl[tid] = P[(size_t)t * 16 + tid];
    __syncthreads();
    size_t xbase = (size_t)t * 4096;
    size_t dbase = (size_t)t * DIM;
#pragma unroll
    for (int j = 0; j < 8; ++j) {
        int d = j * 256 + tid;
        float dtv = b2f(dtb[dbase + d]);
        float xsv = b2f(xz[xbase + d]);
        float zv  = b2f(xz[xbase + DIM + d]);
        float s = 0.f;
#pragma unroll
        for (int n = 0; n < 16; ++n) s += Pl[n] * __expf(A[n * DIM + d] * dtv);
        float y = s * xsv;
        float sz = zv * (1.0f / (1.0f + __expf(-zv)));
        gated[dbase + d] = f2bf(y * sz);
    }
}

// ---------- launch ----------
// ws layout (max 84.1 MB, same footprint as the passing round-1 build):
//   region0 [0, 33.5M):  phase1: wbuf_in bf16 [0,16.7M) + xnb bf16 [16.7M,33.5M)
//                        phase2: dt_acc fp32 (full 33.5M)
//                        phase3: gated bf16 [0,16.7M) + wbuf_out bf16 [16.7M,25.2M)
//   xzb bf16  [33.5M, 67.1M)
//   dtb bf16  [67.1M, 83.9M)   (first 8.4M doubles as wbuf_dt before dt_epi)
//   Pbuf f32  [83.9M, 84.1M)
extern "C" void kernel_launch(void* const* d_in, const int* in_sizes, int n_in,
                              void* d_out, int out_size, void* d_ws, size_t ws_size,
                              hipStream_t stream) {
    const float* x      = (const float*)d_in[0];
    const float* ln_g   = (const float*)d_in[1];
    const float* ln_b   = (const float*)d_in[2];
    const float* W_in   = (const float*)d_in[3];
    const float* b_in   = (const float*)d_in[4];
    const float* stateA = (const float*)d_in[5];
    const float* W_B    = (const float*)d_in[6];
    const float* b_B    = (const float*)d_in[7];
    const float* W_C    = (const float*)d_in[8];
    const float* b_C    = (const float*)d_in[9];
    const float* W_dt   = (const float*)d_in[10];
    const float* b_dt   = (const float*)d_in[11];
    const float* W_out  = (const float*)d_in[12];
    const float* b_out  = (const float*)d_in[13];

    char* ws = (char*)d_ws;
    u16*   wbuf_in  = (u16*)(ws);                    // 16.8 MB
    u16*   xnb      = (u16*)(ws + 16777216);         // 16.8 MB (LN out)
    float* dt_acc   = (float*)(ws);                  // 33.5 MB (aliases wbuf_in+xnb)
    u16*   gated    = (u16*)(ws);                    // 16.8 MB (aliases dt_acc[0:half])
    u16*   wbuf_out = (u16*)(ws + 16777216);         // 8.4 MB (aliases dt_acc upper)
    u16*   xzb      = (u16*)(ws + 33554432);         // 33.5 MB (T x 2D)
    u16*   dtb      = (u16*)(ws + 67108864);         // 16.8 MB (T x D)
    u16*   wbuf_dt  = (u16*)(ws + 67108864);         // 8.4 MB (aliases dtb, dead pre-epi)
    float* Pbuf     = (float*)(ws + 83886080);       // 256 KB (T x 16)

    // 1. W_in -> bf16
    castw_kernel<<<8192, 256, 0, stream>>>(W_in, wbuf_in, 2097152);
    // 2. LN(x) -> bf16
    ln_cast_kernel<<<T_TOK, 256, 0, stream>>>(x, ln_g, ln_b, xnb);
    // 3. xz = xn @ W_in^T + b_in   (T x 4096, bf16)
    gemm_bt<0><<<dim3(32, 32), 256, 0, stream>>>(xnb, 2048, wbuf_in, 2048, b_in,
                                                 nullptr, xzb, 4096, 2048);
    // 4. W_dt -> bf16 (into dtb region; consumed before dt_epi overwrites)
    castw_kernel<<<4096, 256, 0, stream>>>(W_dt, wbuf_dt, 1048576);
    // 5. zero dt accumulator (region0 now dead)
    hipMemsetAsync(dt_acc, 0, 33554432, stream);
    // 6. dt partials: split-K=2, atomic fp32   (T x 2048)
    gemm_bt<3><<<dim3(32, 16, 2), 256, 0, stream>>>(xzb, 4096, wbuf_dt, 2048,
                                                    nullptr, nullptr, dt_acc, 2048, 1024);
    // 7. P[t,n] = Bm*Cm
    bc_kernel<<<1024, 256, 0, stream>>>(xzb, W_B, W_C, b_B, b_C, Pbuf);
    // 8. dt = min(softplus(dt_acc + b_dt), 1) -> bf16
    dt_epi_kernel<<<8192, 256, 0, stream>>>(dt_acc, b_dt, dtb);
    // 9. W_out -> bf16 (dt_acc upper half now dead)
    castw_kernel<<<4096, 256, 0, stream>>>(W_out, wbuf_out, 1048576);
    // 10. zero output accumulator
    hipMemsetAsync(d_out, 0, 33554432, stream);
    // 11. gated (lower half of region0)
    ssm_gate_kernel<<<T_TOK, 256, 0, stream>>>(dtb, xzb, stateA, Pbuf, gated);
    // 12. out partials: split-K=2, atomic fp32 into d_out
    gemm_bt<3><<<dim3(32, 16, 2), 256, 0, stream>>>(gated, 2048, wbuf_out, 2048,
                                                    nullptr, nullptr, (float*)d_out, 2048, 1024);
    // 13. out += b_out + residual
    out_epi_kernel<<<8192, 256, 0, stream>>>((float*)d_out, b_out, x);
}

// Round 3
// 513.273 us; speedup vs baseline: 1.1938x; 1.1938x over previous
//
#include <hip/hip_runtime.h>

typedef unsigned short u16;
typedef float f32x4 __attribute__((ext_vector_type(4)));
typedef __bf16 bf16x8 __attribute__((ext_vector_type(8)));

// ---------- bf16 helpers (RNE) ----------
__device__ __forceinline__ u16 f2bf(float f) {
    unsigned u = __float_as_uint(f);
    u += 0x7FFFu + ((u >> 16) & 1u);
    return (u16)(u >> 16);
}
__device__ __forceinline__ float b2f(u16 h) {
    return __uint_as_float(((unsigned)h) << 16);
}

// ---------- async global->LDS, 16B per lane, wave-uniform LDS base ----------
__device__ __forceinline__ void async16(const u16* g, u16* l) {
    __builtin_amdgcn_global_load_lds(
        (__attribute__((address_space(1))) void*)(u16*)g,
        (__attribute__((address_space(3))) void*)l,
        16, 0, 0);
}

#define T_TOK 4096
#define DIM   2048

// ---------- weight fp32 -> bf16 cast, vectorized (single range) ----------
__global__ __launch_bounds__(256) void castw_kernel(const float* __restrict__ src,
                                                    u16* __restrict__ dst, int n4) {
    int i = blockIdx.x * 256 + threadIdx.x;
    if (i < n4) {
        float4 f = ((const float4*)src)[i];
        ushort4 u;
        u.x = f2bf(f.x); u.y = f2bf(f.y); u.z = f2bf(f.z); u.w = f2bf(f.w);
        ((ushort4*)dst)[i] = u;
    }
}

// ---------- 4-range weight cast (W_dt, W_B, W_C, W_out in one launch) ----------
__global__ __launch_bounds__(256) void cast4_kernel(const float* __restrict__ s0, u16* __restrict__ d0, int n0,
                                                    const float* __restrict__ s1, u16* __restrict__ d1, int n1,
                                                    const float* __restrict__ s2, u16* __restrict__ d2, int n2,
                                                    const float* __restrict__ s3, u16* __restrict__ d3, int n3) {
    int j = blockIdx.x * 256 + threadIdx.x;
    const float* s; u16* d;
    if (j < n0) { s = s0; d = d0; }
    else {
        j -= n0;
        if (j < n1) { s = s1; d = d1; }
        else {
            j -= n1;
            if (j < n2) { s = s2; d = d2; }
            else { j -= n2; if (j >= n3) return; s = s3; d = d3; }
        }
    }
    float4 f = ((const float4*)s)[j];
    ushort4 u;
    u.x = f2bf(f.x); u.y = f2bf(f.y); u.z = f2bf(f.z); u.w = f2bf(f.w);
    ((ushort4*)d)[j] = u;
}

// ---------- LayerNorm + bf16 cast; one block per token, 16B/lane loads ----------
__global__ __launch_bounds__(256) void ln_cast_kernel(const float* __restrict__ x,
                                                      const float* __restrict__ g,
                                                      const float* __restrict__ b,
                                                      u16* __restrict__ o) {
    __shared__ float s1[4], s2[4];
    int t = blockIdx.x, tid = threadIdx.x;
    int wave = tid >> 6, lane = tid & 63;
    size_t base = (size_t)t * DIM;
    int d0 = tid * 8;
    float4 v0 = *(const float4*)(x + base + d0);
    float4 v1 = *(const float4*)(x + base + d0 + 4);
    float v[8] = {v0.x, v0.y, v0.z, v0.w, v1.x, v1.y, v1.z, v1.w};
    float s = 0.f;
#pragma unroll
    for (int j = 0; j < 8; ++j) s += v[j];
#pragma unroll
    for (int o2 = 32; o2; o2 >>= 1) s += __shfl_xor(s, o2);
    if (lane == 0) s1[wave] = s;
    __syncthreads();
    float mu = (s1[0] + s1[1] + s1[2] + s1[3]) * (1.f / DIM);
    float q = 0.f;
#pragma unroll
    for (int j = 0; j < 8; ++j) { float dd = v[j] - mu; q += dd * dd; }
#pragma unroll
    for (int o2 = 32; o2; o2 >>= 1) q += __shfl_xor(q, o2);
    if (lane == 0) s2[wave] = q;
    __syncthreads();
    float var = (s2[0] + s2[1] + s2[2] + s2[3]) * (1.f / DIM);
    float rs = rsqrtf(var + 1e-5f);
    float4 g0 = *(const float4*)(g + d0), g1 = *(const float4*)(g + d0 + 4);
    float4 b0 = *(const float4*)(b + d0), b1 = *(const float4*)(b + d0 + 4);
    float gv[8] = {g0.x, g0.y, g0.z, g0.w, g1.x, g1.y, g1.z, g1.w};
    float bv[8] = {b0.x, b0.y, b0.z, b0.w, b1.x, b1.y, b1.z, b1.w};
    ushort4 r0, r1;
    u16* rp0 = (u16*)&r0; u16* rp1 = (u16*)&r1;
#pragma unroll
    for (int j = 0; j < 4; ++j) {
        rp0[j] = f2bf((v[j] - mu) * rs * gv[j] + bv[j]);
        rp1[j] = f2bf((v[j + 4] - mu) * rs * gv[j + 4] + bv[j + 4]);
    }
    *(ushort4*)(o + base + d0) = r0;
    *(ushort4*)(o + base + d0 + 4) = r1;
}

// ---------- GEMM: C[m,n] = sum_k A[m,k] * W[n,k]  (both row-major bf16) ----------
// 128x128 tile, BK=32, 256 threads = 4 waves (2x2), each wave 4x4 x mfma 16x16x32.
// EPI: 0 = bias+bf16; 1 = bias+min(softplus,1)+bf16, last N-tile stores raw
//          bf16 dots (cols 0..31) instead; 2 = bias+resid+f32.
#define BM 128
#define BN 128
#define BK 32

template <int EPI>
__global__ __launch_bounds__(256) void gemm_bt(const u16* __restrict__ A, int lda,
                                               const u16* __restrict__ W, int ldw,
                                               const float* __restrict__ bias,
                                               const float* __restrict__ resid,
                                               void* __restrict__ C, int ldc, int K,
                                               u16* __restrict__ dots) {
    __shared__ __align__(16) u16 lAB[2 * BM * BK];  // 16 KB: [A 128x32 | W 128x32]
    const int tid = threadIdx.x;
    const int wave = tid >> 6, lane = tid & 63;
    const int quad = lane >> 4, l16 = lane & 15;
    const int tM = blockIdx.x * BM;
    const int tN = blockIdx.y * BN;
    const int wr = wave >> 1, wc = wave & 1;

    // staging: 16 chunks of 1KB; wave w owns chunks w*4..w*4+3. chunks 0-7 = A, 8-15 = W.
    const bool isB = (wave >= 2);
    const u16* src = isB ? W : A;
    const int srcld = isB ? ldw : lda;
    const int rowbase = (isB ? tN : tM) + (wave & 1) * 64 + (lane >> 2);
    const int colofs = (lane & 3) * 8;
    const u16* gptr[4];
    u16* ldst[4];
#pragma unroll
    for (int i = 0; i < 4; ++i) {
        gptr[i] = src + (size_t)(rowbase + i * 16) * srcld + colofs;
        ldst[i] = &lAB[(wave * 4 + i) * 512];
    }

    const u16* lA = lAB;
    const u16* lB = lAB + BM * BK;
    int a_off[4], b_off[4];
#pragma unroll
    for (int i = 0; i < 4; ++i) {
        a_off[i] = (wr * 64 + i * 16 + l16) * BK + quad * 8;
        b_off[i] = (wc * 64 + i * 16 + l16) * BK + quad * 8;
    }

    f32x4 acc[4][4] = {};

    for (int kt = 0; kt < K; kt += BK) {
#pragma unroll
        for (int i = 0; i < 4; ++i) async16(gptr[i] + kt, ldst[i]);
        __syncthreads();  // drains vmcnt(0) before barrier
        bf16x8 af[4], bfr[4];
#pragma unroll
        for (int i = 0; i < 4; ++i) af[i] = *(const bf16x8*)&lA[a_off[i]];
#pragma unroll
        for (int i = 0; i < 4; ++i) bfr[i] = *(const bf16x8*)&lB[b_off[i]];
#pragma unroll
        for (int mi = 0; mi < 4; ++mi)
#pragma unroll
            for (int ni = 0; ni < 4; ++ni)
                acc[mi][ni] = __builtin_amdgcn_mfma_f32_16x16x32_bf16(
                    af[mi], bfr[ni], acc[mi][ni], 0, 0, 0);
        __syncthreads();
    }

    // epilogue: D row = quad*4+r, col = l16 (within each 16x16)
    const bool bcTile = (EPI == 1) && (blockIdx.y == gridDim.y - 1);
#pragma unroll
    for (int mi = 0; mi < 4; ++mi) {
#pragma unroll
        for (int ni = 0; ni < 4; ++ni) {
            int col = tN + wc * 64 + ni * 16 + l16;
            int bcol = bcTile ? 0 : col;       // avoid OOB bias read on BC tile
            float bv = bcTile ? 0.f : bias[bcol];
#pragma unroll
            for (int r = 0; r < 4; ++r) {
                int row = tM + wr * 64 + mi * 16 + quad * 4 + r;
                float v = acc[mi][ni][r] + bv;
                if constexpr (EPI == 0) {
                    ((u16*)C)[(size_t)row * ldc + col] = f2bf(v);
                } else if constexpr (EPI == 1) {
                    if (bcTile) {
                        int nc = col - 2048;   // 0..127; only 0..31 are real dots
                        if (nc < 32) dots[(size_t)row * 32 + nc] = f2bf(v);
                    } else {
                        float sp = (v > 20.f) ? v : log1pf(__expf(v));
                        ((u16*)C)[(size_t)row * ldc + col] = f2bf(fminf(sp, 1.0f));
                    }
                } else {
                    size_t idx = (size_t)row * ldc + col;
                    ((float*)C)[idx] = v + resid[idx];
                }
            }
        }
    }
}

// ---------- fused P + SSM + gate ----------
// P[n] = (Bdot[n]+bB[n])*(Cdot[n]+bC[n]);
// y[d] = xs[d] * sum_n P[n]*exp(A[n,d]*dt[d]);  gated = y * silu(z)
__global__ __launch_bounds__(256) void ssm_gate_kernel(const u16* __restrict__ dtb,
                                                       const u16* __restrict__ xz,
                                                       const float* __restrict__ A,
                                                       const u16* __restrict__ dots,
                                                       const float* __restrict__ bB,
                                                       const float* __restrict__ bC,
                                                       u16* __restrict__ gated) {
    __shared__ float Pl[16];
    int t = blockIdx.x, tid = threadIdx.x;
    if (tid < 16) {
        float Bv = b2f(dots[(size_t)t * 32 + tid]) + bB[tid];
        float Cv = b2f(dots[(size_t)t * 32 + 16 + tid]) + bC[tid];
        Pl[tid] = Bv * Cv;
    }
    __syncthreads();
    size_t xbase = (size_t)t * 4096;
    size_t dbase = (size_t)t * DIM;
    int d0 = tid * 8;
    ushort4 dth[2], xsh[2], zh[2];
    dth[0] = *(const ushort4*)(dtb + dbase + d0);
    dth[1] = *(const ushort4*)(dtb + dbase + d0 + 4);
    xsh[0] = *(const ushort4*)(xz + xbase + d0);
    xsh[1] = *(const ushort4*)(xz + xbase + d0 + 4);
    zh[0]  = *(const ushort4*)(xz + xbase + DIM + d0);
    zh[1]  = *(const ushort4*)(xz + xbase + DIM + d0 + 4);
    float dtv[8], xsv[8], zv[8];
#pragma unroll
    for (int h = 0; h < 2; ++h) {
        const u16* dp = (const u16*)&dth[h];
        const u16* xp = (const u16*)&xsh[h];
        const u16* zp = (const u16*)&zh[h];
#pragma unroll
        for (int j = 0; j < 4; ++j) {
            dtv[h * 4 + j] = b2f(dp[j]);
            xsv[h * 4 + j] = b2f(xp[j]);
            zv[h * 4 + j]  = b2f(zp[j]);
        }
    }
    float s[8] = {};
#pragma unroll
    for (int n = 0; n < 16; ++n) {
        float4 a0 = *(const float4*)(A + n * DIM + d0);
        float4 a1 = *(const float4*)(A + n * DIM + d0 + 4);
        float pn = Pl[n];
        float av[8] = {a0.x, a0.y, a0.z, a0.w, a1.x, a1.y, a1.z, a1.w};
#pragma unroll
        for (int j = 0; j < 8; ++j) s[j] += pn * __expf(av[j] * dtv[j]);
    }
    ushort4 r0, r1;
    u16* rp0 = (u16*)&r0; u16* rp1 = (u16*)&r1;
#pragma unroll
    for (int j = 0; j < 8; ++j) {
        float y = s[j] * xsv[j];
        float sz = zv[j] * (1.0f / (1.0f + __expf(-zv[j])));
        u16 hv = f2bf(y * sz);
        if (j < 4) rp0[j] = hv; else rp1[j - 4] = hv;
    }
    *(ushort4*)(gated + dbase + d0) = r0;
    *(ushort4*)(gated + dbase + d0 + 4) = r1;
}

// ---------- launch ----------
// ws layout (84.15 MB peak, same as the passing round-1 build):
//   R0 [0, 16.78M):       wb_in bf16 (dead after gemm1) -> wb_out bf16 [0, 8.39M)
//   R1 [16.78M, 33.55M):  xnb bf16 (dead after gemm1)
//                         -> wb_dt bf16 2176x2048 [16.78M, 25.70M)  (rows 2048..2079 = W_B,W_C)
//                         -> gated bf16 (after gemm_dt, full R1)
//   R2 [33.55M, 67.11M):  xzb bf16 (T x 2D)
//   R3 [67.11M, 83.89M):  dtb bf16 (T x D)
//   R4 [83.89M, 84.15M):  dots bf16 (T x 32)
extern "C" void kernel_launch(void* const* d_in, const int* in_sizes, int n_in,
                              void* d_out, int out_size, void* d_ws, size_t ws_size,
                              hipStream_t stream) {
    const float* x      = (const float*)d_in[0];
    const float* ln_g   = (const float*)d_in[1];
    const float* ln_b   = (const float*)d_in[2];
    const float* W_in   = (const float*)d_in[3];
    const float* b_in   = (const float*)d_in[4];
    const float* stateA = (const float*)d_in[5];
    const float* W_B    = (const float*)d_in[6];
    const float* b_B    = (const float*)d_in[7];
    const float* W_C    = (const float*)d_in[8];
    const float* b_C    = (const float*)d_in[9];
    const float* W_dt   = (const float*)d_in[10];
    const float* b_dt   = (const float*)d_in[11];
    const float* W_out  = (const float*)d_in[12];
    const float* b_out  = (const float*)d_in[13];

    char* ws = (char*)d_ws;
    u16*   wb_in  = (u16*)(ws);                     // R0: 8.4M elems
    u16*   wb_out = (u16*)(ws);                     // R0 reuse: 4.2M elems
    u16*   xnb    = (u16*)(ws + 16777216);          // R1: 8.4M elems
    u16*   wb_dt  = (u16*)(ws + 16777216);          // R1 reuse: 2176x2048
    u16*   gated  = (u16*)(ws + 16777216);          // R1 reuse: T x D
    u16*   xzb    = (u16*)(ws + 33554432);          // R2: T x 2D
    u16*   dtb    = (u16*)(ws + 67108864);          // R3: T x D
    u16*   dotsb  = (u16*)(ws + 83886080);          // R4: T x 32

    // 1. W_in -> bf16
    castw_kernel<<<8192, 256, 0, stream>>>(W_in, wb_in, 2097152);
    // 2. LN(x) -> bf16
    ln_cast_kernel<<<T_TOK, 256, 0, stream>>>(x, ln_g, ln_b, xnb);
    // 3. xz = xn @ W_in^T + b_in   (T x 4096, bf16)
    gemm_bt<0><<<dim3(32, 32), 256, 0, stream>>>(xnb, 2048, wb_in, 2048, b_in,
                                                 nullptr, xzb, 4096, 2048, nullptr);
    // 4. cast W_dt -> wb_dt rows 0..2047, W_B -> rows 2048..2063, W_C -> 2064..2079,
    //    W_out -> wb_out (R0, wb_in dead). (pad rows 2080..2175 hold poison; outputs discarded)
    cast4_kernel<<<8256, 256, 0, stream>>>(
        W_dt, wb_dt, 1048576,
        W_B,  wb_dt + (size_t)2048 * 2048, 8192,
        W_C,  wb_dt + (size_t)2064 * 2048, 8192,
        W_out, wb_out, 1048576);
    // 5. dt GEMM + BC dots: N = 2176 (17 tiles); last tile -> raw dots
    gemm_bt<1><<<dim3(32, 17), 256, 0, stream>>>(xzb, 4096, wb_dt, 2048, b_dt,
                                                 nullptr, dtb, 2048, 2048, dotsb);
    // 6. fused P + SSM + gate (gated overwrites R1; wb_dt dead)
    ssm_gate_kernel<<<T_TOK, 256, 0, stream>>>(dtb, xzb, stateA, dotsb, b_B, b_C, gated);
    // 7. out = gated @ W_out^T + b_out + x   (T x 2048, f32)
    gemm_bt<2><<<dim3(32, 16), 256, 0, stream>>>(gated, 2048, wb_out, 2048, b_out,
                                                 x, (float*)d_out, 2048, 2048, nullptr);
}

// Round 5
// 470.140 us; speedup vs baseline: 1.3034x; 1.0917x over previous
//
#include <hip/hip_runtime.h>

typedef unsigned short u16;
typedef float f32x4 __attribute__((ext_vector_type(4)));
typedef __bf16 bf16x8 __attribute__((ext_vector_type(8)));

// ---------- bf16 helpers (RNE) ----------
__device__ __forceinline__ u16 f2bf(float f) {
    unsigned u = __float_as_uint(f);
    u += 0x7FFFu + ((u >> 16) & 1u);
    return (u16)(u >> 16);
}
__device__ __forceinline__ float b2f(u16 h) {
    return __uint_as_float(((unsigned)h) << 16);
}

// ---------- async global->LDS, 16B per lane, wave-uniform LDS base ----------
__device__ __forceinline__ void async16(const u16* g, u16* l) {
    __builtin_amdgcn_global_load_lds(
        (__attribute__((address_space(1))) void*)(u16*)g,
        (__attribute__((address_space(3))) void*)l,
        16, 0, 0);
}

#define T_TOK 4096
#define DIM   2048

// ---------- weight fp32 -> bf16 cast ----------
__global__ __launch_bounds__(256) void castw_kernel(const float* __restrict__ src,
                                                    u16* __restrict__ dst, int n4) {
    int i = blockIdx.x * 256 + threadIdx.x;
    if (i < n4) {
        float4 f = ((const float4*)src)[i];
        ushort4 u;
        u.x = f2bf(f.x); u.y = f2bf(f.y); u.z = f2bf(f.z); u.w = f2bf(f.w);
        ((ushort4*)dst)[i] = u;
    }
}

// ---------- 4-range weight cast (W_dt, W_B, W_C, W_out in one launch) ----------
__global__ __launch_bounds__(256) void cast4_kernel(const float* __restrict__ s0, u16* __restrict__ d0, int n0,
                                                    const float* __restrict__ s1, u16* __restrict__ d1, int n1,
                                                    const float* __restrict__ s2, u16* __restrict__ d2, int n2,
                                                    const float* __restrict__ s3, u16* __restrict__ d3, int n3) {
    int j = blockIdx.x * 256 + threadIdx.x;
    const float* s; u16* d;
    if (j < n0) { s = s0; d = d0; }
    else {
        j -= n0;
        if (j < n1) { s = s1; d = d1; }
        else {
            j -= n1;
            if (j < n2) { s = s2; d = d2; }
            else { j -= n2; if (j >= n3) return; s = s3; d = d3; }
        }
    }
    float4 f = ((const float4*)s)[j];
    ushort4 u;
    u.x = f2bf(f.x); u.y = f2bf(f.y); u.z = f2bf(f.z); u.w = f2bf(f.w);
    ((ushort4*)d)[j] = u;
}

// ---------- LayerNorm + bf16 cast; one block per token, 16B/lane ----------
__global__ __launch_bounds__(256) void ln_cast_kernel(const float* __restrict__ x,
                                                      const float* __restrict__ g,
                                                      const float* __restrict__ b,
                                                      u16* __restrict__ o) {
    __shared__ float s1[4], s2[4];
    int t = blockIdx.x, tid = threadIdx.x;
    int wave = tid >> 6, lane = tid & 63;
    size_t base = (size_t)t * DIM;
    int d0 = tid * 8;
    float4 v0 = *(const float4*)(x + base + d0);
    float4 v1 = *(const float4*)(x + base + d0 + 4);
    float v[8] = {v0.x, v0.y, v0.z, v0.w, v1.x, v1.y, v1.z, v1.w};
    float s = 0.f;
#pragma unroll
    for (int j = 0; j < 8; ++j) s += v[j];
#pragma unroll
    for (int o2 = 32; o2; o2 >>= 1) s += __shfl_xor(s, o2);
    if (lane == 0) s1[wave] = s;
    __syncthreads();
    float mu = (s1[0] + s1[1] + s1[2] + s1[3]) * (1.f / DIM);
    float q = 0.f;
#pragma unroll
    for (int j = 0; j < 8; ++j) { float dd = v[j] - mu; q += dd * dd; }
#pragma unroll
    for (int o2 = 32; o2; o2 >>= 1) q += __shfl_xor(q, o2);
    if (lane == 0) s2[wave] = q;
    __syncthreads();
    float var = (s2[0] + s2[1] + s2[2] + s2[3]) * (1.f / DIM);
    float rs = rsqrtf(var + 1e-5f);
    float4 g0 = *(const float4*)(g + d0), g1 = *(const float4*)(g + d0 + 4);
    float4 b0 = *(const float4*)(b + d0), b1 = *(const float4*)(b + d0 + 4);
    float gv[8] = {g0.x, g0.y, g0.z, g0.w, g1.x, g1.y, g1.z, g1.w};
    float bv[8] = {b0.x, b0.y, b0.z, b0.w, b1.x, b1.y, b1.z, b1.w};
    ushort4 r0, r1;
    u16* rp0 = (u16*)&r0; u16* rp1 = (u16*)&r1;
#pragma unroll
    for (int j = 0; j < 4; ++j) {
        rp0[j] = f2bf((v[j] - mu) * rs * gv[j] + bv[j]);
        rp1[j] = f2bf((v[j + 4] - mu) * rs * gv[j + 4] + bv[j + 4]);
    }
    *(ushort4*)(o + base + d0) = r0;
    *(ushort4*)(o + base + d0 + 4) = r1;
}

// ---------- wide GEMM (round-1 structure): 128x128 tile, BK=32 ----------
// C[m,n] = sum_k A[m,k]*W[n,k] + bias[n]; epilogue splits cols: <2048 -> Xs (bf16),
// >=2048 -> Z (bf16). Used only for the input projection (N=4096, 1024 blocks).
#define BM 128
#define BN 128
#define BK 32

__global__ __launch_bounds__(256) void gemm_wide(const u16* __restrict__ A, int lda,
                                                 const u16* __restrict__ W, int ldw,
                                                 const float* __restrict__ bias,
                                                 u16* __restrict__ Xs,
                                                 u16* __restrict__ Z, int K) {
    __shared__ __align__(16) u16 lAB[2 * BM * BK];  // 16 KB
    const int tid = threadIdx.x;
    const int wave = tid >> 6, lane = tid & 63;
    const int quad = lane >> 4, l16 = lane & 15;
    const int tM = blockIdx.x * BM;
    const int tN = blockIdx.y * BN;
    const int wr = wave >> 1, wc = wave & 1;

    const bool isB = (wave >= 2);
    const u16* src = isB ? W : A;
    const int srcld = isB ? ldw : lda;
    const int rowbase = (isB ? tN : tM) + (wave & 1) * 64 + (lane >> 2);
    const int colofs = (lane & 3) * 8;
    const u16* gptr[4];
    u16* ldst[4];
#pragma unroll
    for (int i = 0; i < 4; ++i) {
        gptr[i] = src + (size_t)(rowbase + i * 16) * srcld + colofs;
        ldst[i] = &lAB[(wave * 4 + i) * 512];
    }

    const u16* lA = lAB;
    const u16* lB = lAB + BM * BK;
    int a_off[4], b_off[4];
#pragma unroll
    for (int i = 0; i < 4; ++i) {
        a_off[i] = (wr * 64 + i * 16 + l16) * BK + quad * 8;
        b_off[i] = (wc * 64 + i * 16 + l16) * BK + quad * 8;
    }

    f32x4 acc[4][4] = {};

    for (int kt = 0; kt < K; kt += BK) {
#pragma unroll
        for (int i = 0; i < 4; ++i) async16(gptr[i] + kt, ldst[i]);
        __syncthreads();
        bf16x8 af[4], bfr[4];
#pragma unroll
        for (int i = 0; i < 4; ++i) af[i] = *(const bf16x8*)&lA[a_off[i]];
#pragma unroll
        for (int i = 0; i < 4; ++i) bfr[i] = *(const bf16x8*)&lB[b_off[i]];
#pragma unroll
        for (int mi = 0; mi < 4; ++mi)
#pragma unroll
            for (int ni = 0; ni < 4; ++ni)
                acc[mi][ni] = __builtin_amdgcn_mfma_f32_16x16x32_bf16(
                    af[mi], bfr[ni], acc[mi][ni], 0, 0, 0);
        __syncthreads();
    }

    // D: row = quad*4+r, col = l16. Column range per block is uniform vs 2048.
    const bool isb_z = (tN >= 2048);
    u16* dst = isb_z ? Z : Xs;
#pragma unroll
    for (int mi = 0; mi < 4; ++mi) {
#pragma unroll
        for (int ni = 0; ni < 4; ++ni) {
            int col = tN + wc * 64 + ni * 16 + l16;
            float bv = bias[col];
            int ocol = isb_z ? (col - 2048) : col;
#pragma unroll
            for (int r = 0; r < 4; ++r) {
                int row = tM + wr * 64 + mi * 16 + quad * 4 + r;
                dst[(size_t)row * 2048 + ocol] = f2bf(acc[mi][ni][r] + bv);
            }
        }
    }
}

// ---------- narrow GEMM: BM=128, BN=64, BK=64 (for N~2048 shapes) ----------
// 256 threads = 4 waves (2 row x 2 col); each wave: 4x2 mfma 16x16x32, 2 k-halves.
// EPI 1 = dt: col<2048 -> min(softplus(v),1) bf16; 2048<=col<2080 -> raw dots bf16.
// EPI 2 = out: fp32 v + resid.
#define NBM 128
#define NBN 64
#define NBK 64

template <int EPI>
__global__ __launch_bounds__(256) void gemm_nw(const u16* __restrict__ A, int lda,
                                               const u16* __restrict__ W, int ldw,
                                               const float* __restrict__ bias,
                                               const float* __restrict__ resid,
                                               void* __restrict__ C, int ldc, int K,
                                               u16* __restrict__ dots) {
    __shared__ __align__(16) u16 lAB[(NBM + NBN) * NBK];  // 24 KB, row stride 64
    const int tid = threadIdx.x;
    const int wave = tid >> 6, lane = tid & 63;
    const int quad = lane >> 4, l16 = lane & 15;
    const int tM = blockIdx.x * NBM;
    const int tN = blockIdx.y * NBN;
    const int wr = wave >> 1, wc = wave & 1;

    // staging: 192 rows x 128B. Round i covers rows i*32..i*32+31 (8 lanes/row).
    // Rounds 0-3 = A rows 0..127; rounds 4,5 = B rows 0..63. Wave-uniform LDS base.
    const int rowin = tid >> 3;          // 0..31
    const int col8 = (tid & 7) * 8;
    const u16* gptr[6];
    u16* ldst[6];
#pragma unroll
    for (int i = 0; i < 6; ++i) {
        int trow = i * 32 + rowin;
        const u16* src = (i < 4) ? (A + (size_t)(tM + trow) * lda)
                                 : (W + (size_t)(tN + (trow - NBM)) * ldw);
        gptr[i] = src + col8;
        ldst[i] = &lAB[(i * 32 + wave * 8) * NBK];
    }

    int a_off[2][4], b_off[2][2];
#pragma unroll
    for (int h = 0; h < 2; ++h) {
#pragma unroll
        for (int mi = 0; mi < 4; ++mi)
            a_off[h][mi] = (wr * 64 + mi * 16 + l16) * NBK + h * 32 + quad * 8;
#pragma unroll
        for (int ni = 0; ni < 2; ++ni)
            b_off[h][ni] = (NBM + wc * 32 + ni * 16 + l16) * NBK + h * 32 + quad * 8;
    }

    f32x4 acc[4][2] = {};

    for (int kt = 0; kt < K; kt += NBK) {
#pragma unroll
        for (int i = 0; i < 6; ++i) async16(gptr[i] + kt, ldst[i]);
        __syncthreads();
        bf16x8 af[2][4], bfr[2][2];
#pragma unroll
        for (int h = 0; h < 2; ++h) {
#pragma unroll
            for (int mi = 0; mi < 4; ++mi) af[h][mi] = *(const bf16x8*)&lAB[a_off[h][mi]];
#pragma unroll
            for (int ni = 0; ni < 2; ++ni) bfr[h][ni] = *(const bf16x8*)&lAB[b_off[h][ni]];
        }
#pragma unroll
        for (int h = 0; h < 2; ++h)
#pragma unroll
            for (int mi = 0; mi < 4; ++mi)
#pragma unroll
                for (int ni = 0; ni < 2; ++ni)
                    acc[mi][ni] = __builtin_amdgcn_mfma_f32_16x16x32_bf16(
                        af[h][mi], bfr[h][ni], acc[mi][ni], 0, 0, 0);
        __syncthreads();
    }

#pragma unroll
    for (int mi = 0; mi < 4; ++mi) {
#pragma unroll
        for (int ni = 0; ni < 2; ++ni) {
            int col = tN + wc * 32 + ni * 16 + l16;
            float bv = (EPI == 1 && col >= 2048) ? 0.f : bias[col];
#pragma unroll
            for (int r = 0; r < 4; ++r) {
                int row = tM + wr * 64 + mi * 16 + quad * 4 + r;
                float v = acc[mi][ni][r] + bv;
                if constexpr (EPI == 1) {
                    if (col < 2048) {
                        float sp = (v > 20.f) ? v : log1pf(__expf(v));
                        ((u16*)C)[(size_t)row * ldc + col] = f2bf(fminf(sp, 1.0f));
                    } else if (col < 2080) {
                        dots[(size_t)row * 32 + (col - 2048)] = f2bf(v);
                    }
                } else {
                    size_t idx = (size_t)row * ldc + col;
                    ((float*)C)[idx] = v + resid[idx];
                }
            }
        }
    }
}

// ---------- fused P + SSM + gate (split xs/z inputs) ----------
__global__ __launch_bounds__(256) void ssm_gate_kernel(const u16* __restrict__ dtb,
                                                       const u16* __restrict__ xsb,
                                                       const u16* __restrict__ zb,
                                                       const float* __restrict__ A,
                                                       const u16* __restrict__ dots,
                                                       const float* __restrict__ bB,
                                                       const float* __restrict__ bC,
                                                       u16* __restrict__ gated) {
    __shared__ float Pl[16];
    int t = blockIdx.x, tid = threadIdx.x;
    if (tid < 16) {
        float Bv = b2f(dots[(size_t)t * 32 + tid]) + bB[tid];
        float Cv = b2f(dots[(size_t)t * 32 + 16 + tid]) + bC[tid];
        Pl[tid] = Bv * Cv;
    }
    __syncthreads();
    size_t dbase = (size_t)t * DIM;
    int d0 = tid * 8;
    ushort4 dth[2], xsh[2], zh[2];
    dth[0] = *(const ushort4*)(dtb + dbase + d0);
    dth[1] = *(const ushort4*)(dtb + dbase + d0 + 4);
    xsh[0] = *(const ushort4*)(xsb + dbase + d0);
    xsh[1] = *(const ushort4*)(xsb + dbase + d0 + 4);
    zh[0]  = *(const ushort4*)(zb + dbase + d0);
    zh[1]  = *(const ushort4*)(zb + dbase + d0 + 4);
    float dtv[8], xsv[8], zv[8];
#pragma unroll
    for (int h = 0; h < 2; ++h) {
        const u16* dp = (const u16*)&dth[h];
        const u16* xp = (const u16*)&xsh[h];
        const u16* zp = (const u16*)&zh[h];
#pragma unroll
        for (int j = 0; j < 4; ++j) {
            dtv[h * 4 + j] = b2f(dp[j]);
            xsv[h * 4 + j] = b2f(xp[j]);
            zv[h * 4 + j]  = b2f(zp[j]);
        }
    }
    float s[8] = {};
#pragma unroll
    for (int n = 0; n < 16; ++n) {
        float4 a0 = *(const float4*)(A + n * DIM + d0);
        float4 a1 = *(const float4*)(A + n * DIM + d0 + 4);
        float pn = Pl[n];
        float av[8] = {a0.x, a0.y, a0.z, a0.w, a1.x, a1.y, a1.z, a1.w};
#pragma unroll
        for (int j = 0; j < 8; ++j) s[j] += pn * __expf(av[j] * dtv[j]);
    }
    ushort4 r0, r1;
    u16* rp0 = (u16*)&r0; u16* rp1 = (u16*)&r1;
#pragma unroll
    for (int j = 0; j < 8; ++j) {
        float y = s[j] * xsv[j];
        float sz = zv[j] * (1.0f / (1.0f + __expf(-zv[j])));
        u16 hv = f2bf(y * sz);
        if (j < 4) rp0[j] = hv; else rp1[j - 4] = hv;
    }
    *(ushort4*)(gated + dbase + d0) = r0;
    *(ushort4*)(gated + dbase + d0 + 4) = r1;
}

// ---------- launch ----------
// ws layout (84.15 MB peak):
//   R0 [0, 16.78M):       wb_in bf16 -> after gemm1: wb_out bf16 [0, 8.39M)
//   R1 [16.78M, 33.55M):  xnb bf16 -> wb_dt bf16 2112x2048 [16.78M, 25.43M)
//                         -> gated bf16 (after dt gemm, full R1)
//   R2 [33.55M, 50.33M):  xsb bf16 (T x D)
//   R3 [50.33M, 67.11M):  zb  bf16 (T x D)
//   R4 [67.11M, 83.89M):  dtb bf16 (T x D)
//   R5 [83.89M, 84.15M):  dots bf16 (T x 32)
extern "C" void kernel_launch(void* const* d_in, const int* in_sizes, int n_in,
                              void* d_out, int out_size, void* d_ws, size_t ws_size,
                              hipStream_t stream) {
    const float* x      = (const float*)d_in[0];
    const float* ln_g   = (const float*)d_in[1];
    const float* ln_b   = (const float*)d_in[2];
    const float* W_in   = (const float*)d_in[3];
    const float* b_in   = (const float*)d_in[4];
    const float* stateA = (const float*)d_in[5];
    const float* W_B    = (const float*)d_in[6];
    const float* b_B    = (const float*)d_in[7];
    const float* W_C    = (const float*)d_in[8];
    const float* b_C    = (const float*)d_in[9];
    const float* W_dt   = (const float*)d_in[10];
    const float* b_dt   = (const float*)d_in[11];
    const float* W_out  = (const float*)d_in[12];
    const float* b_out  = (const float*)d_in[13];

    char* ws = (char*)d_ws;
    u16*   wb_in  = (u16*)(ws);                     // R0
    u16*   wb_out = (u16*)(ws);                     // R0 reuse (8.4 MB)
    u16*   xnb    = (u16*)(ws + 16777216);          // R1
    u16*   wb_dt  = (u16*)(ws + 16777216);          // R1 reuse: 2112 x 2048
    u16*   gated  = (u16*)(ws + 16777216);          // R1 reuse: T x D
    u16*   xsb    = (u16*)(ws + 33554432);          // R2: T x D
    u16*   zb     = (u16*)(ws + 50331648);          // R3: T x D
    u16*   dtb    = (u16*)(ws + 67108864);          // R4: T x D
    u16*   dotsb  = (u16*)(ws + 83886080);          // R5: T x 32

    // 1. W_in -> bf16
    castw_kernel<<<8192, 256, 0, stream>>>(W_in, wb_in, 2097152);
    // 2. LN(x) -> bf16
    ln_cast_kernel<<<T_TOK, 256, 0, stream>>>(x, ln_g, ln_b, xnb);
    // 3. xz = xn @ W_in^T + b_in, split into xsb | zb
    gemm_wide<<<dim3(32, 32), 256, 0, stream>>>(xnb, 2048, wb_in, 2048, b_in,
                                                xsb, zb, 2048);
    // 4. cast W_dt -> wb_dt rows 0..2047, W_B -> 2048..2063, W_C -> 2064..2079,
    //    W_out -> wb_out (R0). Pad rows 2080..2111 hold poison; outputs discarded.
    cast4_kernel<<<8256, 256, 0, stream>>>(
        W_dt, wb_dt, 1048576,
        W_B,  wb_dt + (size_t)2048 * 2048, 8192,
        W_C,  wb_dt + (size_t)2064 * 2048, 8192,
        W_out, wb_out, 1048576);
    // 5. dt GEMM + BC dots: narrow tiles, N = 2112 (33 tiles), 1056 blocks
    gemm_nw<1><<<dim3(32, 33), 256, 0, stream>>>(xsb, 2048, wb_dt, 2048, b_dt,
                                                 nullptr, dtb, 2048, 2048, dotsb);
    // 6. fused P + SSM + gate (gated overwrites R1; wb_dt dead)
    ssm_gate_kernel<<<T_TOK, 256, 0, stream>>>(dtb, xsb, zb, stateA, dotsb,
                                               b_B, b_C, gated);
    // 7. out = gated @ W_out^T + b_out + x, narrow tiles, 1024 blocks
    gemm_nw<2><<<dim3(32, 32), 256, 0, stream>>>(gated, 2048, wb_out, 2048, b_out,
                                                 x, (float*)d_out, 2048, 2048, nullptr);
}

// Round 6
// 434.781 us; speedup vs baseline: 1.4094x; 1.0813x over previous
//
#include <hip/hip_runtime.h>

typedef unsigned short u16;
typedef float f32x4 __attribute__((ext_vector_type(4)));
typedef __bf16 bf16x8 __attribute__((ext_vector_type(8)));

// ---------- bf16 helpers (RNE) ----------
__device__ __forceinline__ u16 f2bf(float f) {
    unsigned u = __float_as_uint(f);
    u += 0x7FFFu + ((u >> 16) & 1u);
    return (u16)(u >> 16);
}
__device__ __forceinline__ float b2f(u16 h) {
    return __uint_as_float(((unsigned)h) << 16);
}

// ---------- async global->LDS, 16B per lane, wave-uniform LDS base ----------
__device__ __forceinline__ void async16(const u16* g, u16* l) {
    __builtin_amdgcn_global_load_lds(
        (__attribute__((address_space(1))) void*)(u16*)g,
        (__attribute__((address_space(3))) void*)l,
        16, 0, 0);
}

#define T_TOK 4096
#define DIM   2048

// ---------- weight fp32 -> bf16 cast ----------
__global__ __launch_bounds__(256) void castw_kernel(const float* __restrict__ src,
                                                    u16* __restrict__ dst, int n4) {
    int i = blockIdx.x * 256 + threadIdx.x;
    if (i < n4) {
        float4 f = ((const float4*)src)[i];
        ushort4 u;
        u.x = f2bf(f.x); u.y = f2bf(f.y); u.z = f2bf(f.z); u.w = f2bf(f.w);
        ((ushort4*)dst)[i] = u;
    }
}

// ---------- 4-range weight cast (W_dt, W_B, W_C, W_out in one launch) ----------
__global__ __launch_bounds__(256) void cast4_kernel(const float* __restrict__ s0, u16* __restrict__ d0, int n0,
                                                    const float* __restrict__ s1, u16* __restrict__ d1, int n1,
                                                    const float* __restrict__ s2, u16* __restrict__ d2, int n2,
                                                    const float* __restrict__ s3, u16* __restrict__ d3, int n3) {
    int j = blockIdx.x * 256 + threadIdx.x;
    const float* s; u16* d;
    if (j < n0) { s = s0; d = d0; }
    else {
        j -= n0;
        if (j < n1) { s = s1; d = d1; }
        else {
            j -= n1;
            if (j < n2) { s = s2; d = d2; }
            else { j -= n2; if (j >= n3) return; s = s3; d = d3; }
        }
    }
    float4 f = ((const float4*)s)[j];
    ushort4 u;
    u.x = f2bf(f.x); u.y = f2bf(f.y); u.z = f2bf(f.z); u.w = f2bf(f.w);
    ((ushort4*)d)[j] = u;
}

// ---------- LayerNorm + bf16 cast; one block per token, 16B/lane ----------
__global__ __launch_bounds__(256) void ln_cast_kernel(const float* __restrict__ x,
                                                      const float* __restrict__ g,
                                                      const float* __restrict__ b,
                                                      u16* __restrict__ o) {
    __shared__ float s1[4], s2[4];
    int t = blockIdx.x, tid = threadIdx.x;
    int wave = tid >> 6, lane = tid & 63;
    size_t base = (size_t)t * DIM;
    int d0 = tid * 8;
    float4 v0 = *(const float4*)(x + base + d0);
    float4 v1 = *(const float4*)(x + base + d0 + 4);
    float v[8] = {v0.x, v0.y, v0.z, v0.w, v1.x, v1.y, v1.z, v1.w};
    float s = 0.f;
#pragma unroll
    for (int j = 0; j < 8; ++j) s += v[j];
#pragma unroll
    for (int o2 = 32; o2; o2 >>= 1) s += __shfl_xor(s, o2);
    if (lane == 0) s1[wave] = s;
    __syncthreads();
    float mu = (s1[0] + s1[1] + s1[2] + s1[3]) * (1.f / DIM);
    float q = 0.f;
#pragma unroll
    for (int j = 0; j < 8; ++j) { float dd = v[j] - mu; q += dd * dd; }
#pragma unroll
    for (int o2 = 32; o2; o2 >>= 1) q += __shfl_xor(q, o2);
    if (lane == 0) s2[wave] = q;
    __syncthreads();
    float var = (s2[0] + s2[1] + s2[2] + s2[3]) * (1.f / DIM);
    float rs = rsqrtf(var + 1e-5f);
    float4 g0 = *(const float4*)(g + d0), g1 = *(const float4*)(g + d0 + 4);
    float4 b0 = *(const float4*)(b + d0), b1 = *(const float4*)(b + d0 + 4);
    float gv[8] = {g0.x, g0.y, g0.z, g0.w, g1.x, g1.y, g1.z, g1.w};
    float bv[8] = {b0.x, b0.y, b0.z, b0.w, b1.x, b1.y, b1.z, b1.w};
    ushort4 r0, r1;
    u16* rp0 = (u16*)&r0; u16* rp1 = (u16*)&r1;
#pragma unroll
    for (int j = 0; j < 4; ++j) {
        rp0[j] = f2bf((v[j] - mu) * rs * gv[j] + bv[j]);
        rp1[j] = f2bf((v[j + 4] - mu) * rs * gv[j + 4] + bv[j + 4]);
    }
    *(ushort4*)(o + base + d0) = r0;
    *(ushort4*)(o + base + d0 + 4) = r1;
}

// ---------- wide GEMM (round-1 structure): 128x128 tile, BK=32 ----------
// C[m,n] = sum_k A[m,k]*W[n,k] + bias[n]; epilogue splits cols: <2048 -> Xs (bf16),
// >=2048 -> Z (bf16). Used only for the input projection (N=4096, 1024 blocks).
// NOTE: has 8-way LDS read conflicts (8.4M cyc) — measured hidden under the
// barrier drain (round 2: removing them changed nothing). Leave as is.
#define BM 128
#define BN 128
#define BK 32

__global__ __launch_bounds__(256) void gemm_wide(const u16* __restrict__ A, int lda,
                                                 const u16* __restrict__ W, int ldw,
                                                 const float* __restrict__ bias,
                                                 u16* __restrict__ Xs,
                                                 u16* __restrict__ Z, int K) {
    __shared__ __align__(16) u16 lAB[2 * BM * BK];  // 16 KB
    const int tid = threadIdx.x;
    const int wave = tid >> 6, lane = tid & 63;
    const int quad = lane >> 4, l16 = lane & 15;
    const int tM = blockIdx.x * BM;
    const int tN = blockIdx.y * BN;
    const int wr = wave >> 1, wc = wave & 1;

    const bool isB = (wave >= 2);
    const u16* src = isB ? W : A;
    const int srcld = isB ? ldw : lda;
    const int rowbase = (isB ? tN : tM) + (wave & 1) * 64 + (lane >> 2);
    const int colofs = (lane & 3) * 8;
    const u16* gptr[4];
    u16* ldst[4];
#pragma unroll
    for (int i = 0; i < 4; ++i) {
        gptr[i] = src + (size_t)(rowbase + i * 16) * srcld + colofs;
        ldst[i] = &lAB[(wave * 4 + i) * 512];
    }

    const u16* lA = lAB;
    const u16* lB = lAB + BM * BK;
    int a_off[4], b_off[4];
#pragma unroll
    for (int i = 0; i < 4; ++i) {
        a_off[i] = (wr * 64 + i * 16 + l16) * BK + quad * 8;
        b_off[i] = (wc * 64 + i * 16 + l16) * BK + quad * 8;
    }

    f32x4 acc[4][4] = {};

    for (int kt = 0; kt < K; kt += BK) {
#pragma unroll
        for (int i = 0; i < 4; ++i) async16(gptr[i] + kt, ldst[i]);
        __syncthreads();
        bf16x8 af[4], bfr[4];
#pragma unroll
        for (int i = 0; i < 4; ++i) af[i] = *(const bf16x8*)&lA[a_off[i]];
#pragma unroll
        for (int i = 0; i < 4; ++i) bfr[i] = *(const bf16x8*)&lB[b_off[i]];
#pragma unroll
        for (int mi = 0; mi < 4; ++mi)
#pragma unroll
            for (int ni = 0; ni < 4; ++ni)
                acc[mi][ni] = __builtin_amdgcn_mfma_f32_16x16x32_bf16(
                    af[mi], bfr[ni], acc[mi][ni], 0, 0, 0);
        __syncthreads();
    }

    // D: row = quad*4+r, col = l16. Column range per block is uniform vs 2048.
    const bool isb_z = (tN >= 2048);
    u16* dst = isb_z ? Z : Xs;
#pragma unroll
    for (int mi = 0; mi < 4; ++mi) {
#pragma unroll
        for (int ni = 0; ni < 4; ++ni) {
            int col = tN + wc * 64 + ni * 16 + l16;
            float bv = bias[col];
            int ocol = isb_z ? (col - 2048) : col;
#pragma unroll
            for (int r = 0; r < 4; ++r) {
                int row = tM + wr * 64 + mi * 16 + quad * 4 + r;
                dst[(size_t)row * 2048 + ocol] = f2bf(acc[mi][ni][r] + bv);
            }
        }
    }
}

// ---------- narrow GEMM: BM=128, BN=64, BK=64 (for N~2048 shapes) ----------
// 256 threads = 4 waves (2 row x 2 col); each wave: 4x2 mfma 16x16x32, 2 k-halves.
// LDS rows are 128 B = exactly 32 banks, so unswizzled reads are 16-way
// conflicted (measured 19.46M cyc, ~21% of wall). XOR swizzle: 16B chunk c of
// row R lives at slot c ^ (R & 7) -> read phases are 2-way (free, m136).
// Staging side implements the swizzle as a per-lane permutation of the global
// pointer within each 128 B row (wave-uniform LDS base preserved).
// EPI 1 = dt: col<2048 -> min(softplus(v),1) bf16; 2048<=col<2080 -> raw dots bf16.
// EPI 2 = out: fp32 v + resid.
#define NBM 128
#define NBN 64
#define NBK 64

template <int EPI>
__global__ __launch_bounds__(256) void gemm_nw(const u16* __restrict__ A, int lda,
                                               const u16* __restrict__ W, int ldw,
                                               const float* __restrict__ bias,
                                               const float* __restrict__ resid,
                                               void* __restrict__ C, int ldc, int K,
                                               u16* __restrict__ dots) {
    __shared__ __align__(16) u16 lAB[(NBM + NBN) * NBK];  // 24 KB, row stride 64
    const int tid = threadIdx.x;
    const int wave = tid >> 6, lane = tid & 63;
    const int quad = lane >> 4, l16 = lane & 15;
    const int tM = blockIdx.x * NBM;
    const int tN = blockIdx.y * NBN;
    const int wr = wave >> 1, wc = wave & 1;

    // staging: 192 rows x 128B. Round i covers rows i*32..i*32+31 (8 lanes/row).
    // Rounds 0-3 = A rows 0..127; rounds 4,5 = B rows 0..63.
    const int rowin = tid >> 3;                    // 0..31
    const int r3 = rowin & 7;                      // swizzle key (row low bits)
    const int col8 = ((tid & 7) ^ r3) * 8;         // swizzled source chunk
    const u16* gptr[6];
    u16* ldst[6];
#pragma unroll
    for (int i = 0; i < 6; ++i) {
        int trow = i * 32 + rowin;
        const u16* src = (i < 4) ? (A + (size_t)(tM + trow) * lda)
                                 : (W + (size_t)(tN + (trow - NBM)) * ldw);
        gptr[i] = src + col8;
        ldst[i] = &lAB[(i * 32 + wave * 8) * NBK];
    }

    int a_off[2][4], b_off[2][2];
#pragma unroll
    for (int h = 0; h < 2; ++h) {
#pragma unroll
        for (int mi = 0; mi < 4; ++mi)
            a_off[h][mi] = (wr * 64 + mi * 16 + l16) * NBK +
                           (((h * 4 + quad) ^ (l16 & 7)) * 8);
#pragma unroll
        for (int ni = 0; ni < 2; ++ni)
            b_off[h][ni] = (NBM + wc * 32 + ni * 16 + l16) * NBK +
                           (((h * 4 + quad) ^ (l16 & 7)) * 8);
    }

    f32x4 acc[4][2] = {};

    for (int kt = 0; kt < K; kt += NBK) {
#pragma unroll
        for (int i = 0; i < 6; ++i) async16(gptr[i] + kt, ldst[i]);
        __syncthreads();
        bf16x8 af[2][4], bfr[2][2];
#pragma unroll
        for (int h = 0; h < 2; ++h) {
#pragma unroll
            for (int mi = 0; mi < 4; ++mi) af[h][mi] = *(const bf16x8*)&lAB[a_off[h][mi]];
#pragma unroll
            for (int ni = 0; ni < 2; ++ni) bfr[h][ni] = *(const bf16x8*)&lAB[b_off[h][ni]];
        }
#pragma unroll
        for (int h = 0; h < 2; ++h)
#pragma unroll
            for (int mi = 0; mi < 4; ++mi)
#pragma unroll
                for (int ni = 0; ni < 2; ++ni)
                    acc[mi][ni] = __builtin_amdgcn_mfma_f32_16x16x32_bf16(
                        af[h][mi], bfr[h][ni], acc[mi][ni], 0, 0, 0);
        __syncthreads();
    }

#pragma unroll
    for (int mi = 0; mi < 4; ++mi) {
#pragma unroll
        for (int ni = 0; ni < 2; ++ni) {
            int col = tN + wc * 32 + ni * 16 + l16;
            float bv = (EPI == 1 && col >= 2048) ? 0.f : bias[col];
#pragma unroll
            for (int r = 0; r < 4; ++r) {
                int row = tM + wr * 64 + mi * 16 + quad * 4 + r;
                float v = acc[mi][ni][r] + bv;
                if constexpr (EPI == 1) {
                    if (col < 2048) {
                        float sp = (v > 20.f) ? v : log1pf(__expf(v));
                        ((u16*)C)[(size_t)row * ldc + col] = f2bf(fminf(sp, 1.0f));
                    } else if (col < 2080) {
                        dots[(size_t)row * 32 + (col - 2048)] = f2bf(v);
                    }
                } else {
                    size_t idx = (size_t)row * ldc + col;
                    ((float*)C)[idx] = v + resid[idx];
                }
            }
        }
    }
}

// ---------- fused P + SSM + gate (split xs/z inputs) ----------
__global__ __launch_bounds__(256) void ssm_gate_kernel(const u16* __restrict__ dtb,
                                                       const u16* __restrict__ xsb,
                                                       const u16* __restrict__ zb,
                                                       const float* __restrict__ A,
                                                       const u16* __restrict__ dots,
                                                       const float* __restrict__ bB,
                                                       const float* __restrict__ bC,
                                                       u16* __restrict__ gated) {
    __shared__ float Pl[16];
    int t = blockIdx.x, tid = threadIdx.x;
    if (tid < 16) {
        float Bv = b2f(dots[(size_t)t * 32 + tid]) + bB[tid];
        float Cv = b2f(dots[(size_t)t * 32 + 16 + tid]) + bC[tid];
        Pl[tid] = Bv * Cv;
    }
    __syncthreads();
    size_t dbase = (size_t)t * DIM;
    int d0 = tid * 8;
    ushort4 dth[2], xsh[2], zh[2];
    dth[0] = *(const ushort4*)(dtb + dbase + d0);
    dth[1] = *(const ushort4*)(dtb + dbase + d0 + 4);
    xsh[0] = *(const ushort4*)(xsb + dbase + d0);
    xsh[1] = *(const ushort4*)(xsb + dbase + d0 + 4);
    zh[0]  = *(const ushort4*)(zb + dbase + d0);
    zh[1]  = *(const ushort4*)(zb + dbase + d0 + 4);
    float dtv[8], xsv[8], zv[8];
#pragma unroll
    for (int h = 0; h < 2; ++h) {
        const u16* dp = (const u16*)&dth[h];
        const u16* xp = (const u16*)&xsh[h];
        const u16* zp = (const u16*)&zh[h];
#pragma unroll
        for (int j = 0; j < 4; ++j) {
            dtv[h * 4 + j] = b2f(dp[j]);
            xsv[h * 4 + j] = b2f(xp[j]);
            zv[h * 4 + j]  = b2f(zp[j]);
        }
    }
    float s[8] = {};
#pragma unroll
    for (int n = 0; n < 16; ++n) {
        float4 a0 = *(const float4*)(A + n * DIM + d0);
        float4 a1 = *(const float4*)(A + n * DIM + d0 + 4);
        float pn = Pl[n];
        float av[8] = {a0.x, a0.y, a0.z, a0.w, a1.x, a1.y, a1.z, a1.w};
#pragma unroll
        for (int j = 0; j < 8; ++j) s[j] += pn * __expf(av[j] * dtv[j]);
    }
    ushort4 r0, r1;
    u16* rp0 = (u16*)&r0; u16* rp1 = (u16*)&r1;
#pragma unroll
    for (int j = 0; j < 8; ++j) {
        float y = s[j] * xsv[j];
        float sz = zv[j] * (1.0f / (1.0f + __expf(-zv[j])));
        u16 hv = f2bf(y * sz);
        if (j < 4) rp0[j] = hv; else rp1[j - 4] = hv;
    }
    *(ushort4*)(gated + dbase + d0) = r0;
    *(ushort4*)(gated + dbase + d0 + 4) = r1;
}

// ---------- launch ----------
// ws layout (84.15 MB peak):
//   R0 [0, 16.78M):       wb_in bf16 -> after gemm1: wb_out bf16 [0, 8.39M)
//   R1 [16.78M, 33.55M):  xnb bf16 -> wb_dt bf16 2112x2048 [16.78M, 25.43M)
//                         -> gated bf16 (after dt gemm, full R1)
//   R2 [33.55M, 50.33M):  xsb bf16 (T x D)
//   R3 [50.33M, 67.11M):  zb  bf16 (T x D)
//   R4 [67.11M, 83.89M):  dtb bf16 (T x D)
//   R5 [83.89M, 84.15M):  dots bf16 (T x 32)
extern "C" void kernel_launch(void* const* d_in, const int* in_sizes, int n_in,
                              void* d_out, int out_size, void* d_ws, size_t ws_size,
                              hipStream_t stream) {
    const float* x      = (const float*)d_in[0];
    const float* ln_g   = (const float*)d_in[1];
    const float* ln_b   = (const float*)d_in[2];
    const float* W_in   = (const float*)d_in[3];
    const float* b_in   = (const float*)d_in[4];
    const float* stateA = (const float*)d_in[5];
    const float* W_B    = (const float*)d_in[6];
    const float* b_B    = (const float*)d_in[7];
    const float* W_C    = (const float*)d_in[8];
    const float* b_C    = (const float*)d_in[9];
    const float* W_dt   = (const float*)d_in[10];
    const float* b_dt   = (const float*)d_in[11];
    const float* W_out  = (const float*)d_in[12];
    const float* b_out  = (const float*)d_in[13];

    char* ws = (char*)d_ws;
    u16*   wb_in  = (u16*)(ws);                     // R0
    u16*   wb_out = (u16*)(ws);                     // R0 reuse (8.4 MB)
    u16*   xnb    = (u16*)(ws + 16777216);          // R1
    u16*   wb_dt  = (u16*)(ws + 16777216);          // R1 reuse: 2112 x 2048
    u16*   gated  = (u16*)(ws + 16777216);          // R1 reuse: T x D
    u16*   xsb    = (u16*)(ws + 33554432);          // R2: T x D
    u16*   zb     = (u16*)(ws + 50331648);          // R3: T x D
    u16*   dtb    = (u16*)(ws + 67108864);          // R4: T x D
    u16*   dotsb  = (u16*)(ws + 83886080);          // R5: T x 32

    // 1. W_in -> bf16
    castw_kernel<<<8192, 256, 0, stream>>>(W_in, wb_in, 2097152);
    // 2. LN(x) -> bf16
    ln_cast_kernel<<<T_TOK, 256, 0, stream>>>(x, ln_g, ln_b, xnb);
    // 3. xz = xn @ W_in^T + b_in, split into xsb | zb
    gemm_wide<<<dim3(32, 32), 256, 0, stream>>>(xnb, 2048, wb_in, 2048, b_in,
                                                xsb, zb, 2048);
    // 4. cast W_dt -> wb_dt rows 0..2047, W_B -> 2048..2063, W_C -> 2064..2079,
    //    W_out -> wb_out (R0). Pad rows 2080..2111 hold poison; outputs discarded.
    cast4_kernel<<<8256, 256, 0, stream>>>(
        W_dt, wb_dt, 1048576,
        W_B,  wb_dt + (size_t)2048 * 2048, 8192,
        W_C,  wb_dt + (size_t)2064 * 2048, 8192,
        W_out, wb_out, 1048576);
    // 5. dt GEMM + BC dots: narrow tiles, N = 2112 (33 tiles), 1056 blocks
    gemm_nw<1><<<dim3(32, 33), 256, 0, stream>>>(xsb, 2048, wb_dt, 2048, b_dt,
                                                 nullptr, dtb, 2048, 2048, dotsb);
    // 6. fused P + SSM + gate (gated overwrites R1; wb_dt dead)
    ssm_gate_kernel<<<T_TOK, 256, 0, stream>>>(dtb, xsb, zb, stateA, dotsb,
                                               b_B, b_C, gated);
    // 7. out = gated @ W_out^T + b_out + x, narrow tiles, 1024 blocks
    gemm_nw<2><<<dim3(32, 32), 256, 0, stream>>>(gated, 2048, wb_out, 2048, b_out,
                                                 x, (float*)d_out, 2048, 2048, nullptr);
}

// Round 7
// 394.904 us; speedup vs baseline: 1.5517x; 1.1010x over previous
//
#include <hip/hip_runtime.h>

typedef unsigned short u16;
typedef float f32x4 __attribute__((ext_vector_type(4)));
typedef __bf16 bf16x8 __attribute__((ext_vector_type(8)));

// ---------- bf16 helpers (RNE) ----------
__device__ __forceinline__ u16 f2bf(float f) {
    unsigned u = __float_as_uint(f);
    u += 0x7FFFu + ((u >> 16) & 1u);
    return (u16)(u >> 16);
}
__device__ __forceinline__ float b2f(u16 h) {
    return __uint_as_float(((unsigned)h) << 16);
}

// ---------- async global->LDS, 16B per lane, wave-uniform LDS base ----------
__device__ __forceinline__ void async16(const u16* g, u16* l) {
    __builtin_amdgcn_global_load_lds(
        (__attribute__((address_space(1))) void*)(u16*)g,
        (__attribute__((address_space(3))) void*)l,
        16, 0, 0);
}

#define T_TOK 4096
#define DIM   2048

// ---------- fused: W_in cast (blocks 0..8191) + LayerNorm (blocks 8192..12287) ----------
__global__ __launch_bounds__(256) void castln_kernel(const float* __restrict__ W_in,
                                                     u16* __restrict__ wb_in,
                                                     const float* __restrict__ x,
                                                     const float* __restrict__ g,
                                                     const float* __restrict__ b,
                                                     u16* __restrict__ o) {
    __shared__ float s1[4], s2[4];
    int blk = blockIdx.x, tid = threadIdx.x;
    if (blk < 8192) {               // cast path: 2,097,152 float4s
        int i = blk * 256 + tid;
        float4 f = ((const float4*)W_in)[i];
        ushort4 u;
        u.x = f2bf(f.x); u.y = f2bf(f.y); u.z = f2bf(f.z); u.w = f2bf(f.w);
        ((ushort4*)wb_in)[i] = u;
        return;
    }
    int t = blk - 8192;
    int wave = tid >> 6, lane = tid & 63;
    size_t base = (size_t)t * DIM;
    int d0 = tid * 8;
    float4 v0 = *(const float4*)(x + base + d0);
    float4 v1 = *(const float4*)(x + base + d0 + 4);
    float v[8] = {v0.x, v0.y, v0.z, v0.w, v1.x, v1.y, v1.z, v1.w};
    float s = 0.f;
#pragma unroll
    for (int j = 0; j < 8; ++j) s += v[j];
#pragma unroll
    for (int o2 = 32; o2; o2 >>= 1) s += __shfl_xor(s, o2);
    if (lane == 0) s1[wave] = s;
    __syncthreads();
    float mu = (s1[0] + s1[1] + s1[2] + s1[3]) * (1.f / DIM);
    float q = 0.f;
#pragma unroll
    for (int j = 0; j < 8; ++j) { float dd = v[j] - mu; q += dd * dd; }
#pragma unroll
    for (int o2 = 32; o2; o2 >>= 1) q += __shfl_xor(q, o2);
    if (lane == 0) s2[wave] = q;
    __syncthreads();
    float var = (s2[0] + s2[1] + s2[2] + s2[3]) * (1.f / DIM);
    float rs = rsqrtf(var + 1e-5f);
    float4 g0 = *(const float4*)(g + d0), g1 = *(const float4*)(g + d0 + 4);
    float4 b0 = *(const float4*)(b + d0), b1 = *(const float4*)(b + d0 + 4);
    float gv[8] = {g0.x, g0.y, g0.z, g0.w, g1.x, g1.y, g1.z, g1.w};
    float bv[8] = {b0.x, b0.y, b0.z, b0.w, b1.x, b1.y, b1.z, b1.w};
    ushort4 r0, r1;
    u16* rp0 = (u16*)&r0; u16* rp1 = (u16*)&r1;
#pragma unroll
    for (int j = 0; j < 4; ++j) {
        rp0[j] = f2bf((v[j] - mu) * rs * gv[j] + bv[j]);
        rp1[j] = f2bf((v[j + 4] - mu) * rs * gv[j + 4] + bv[j + 4]);
    }
    *(ushort4*)(o + base + d0) = r0;
    *(ushort4*)(o + base + d0 + 4) = r1;
}

// ---------- 4-range weight cast (W_dt, W_B, W_C, W_out in one launch) ----------
__global__ __launch_bounds__(256) void cast4_kernel(const float* __restrict__ s0, u16* __restrict__ d0, int n0,
                                                    const float* __restrict__ s1, u16* __restrict__ d1, int n1,
                                                    const float* __restrict__ s2, u16* __restrict__ d2, int n2,
                                                    const float* __restrict__ s3, u16* __restrict__ d3, int n3) {
    int j = blockIdx.x * 256 + threadIdx.x;
    const float* s; u16* d;
    if (j < n0) { s = s0; d = d0; }
    else {
        j -= n0;
        if (j < n1) { s = s1; d = d1; }
        else {
            j -= n1;
            if (j < n2) { s = s2; d = d2; }
            else { j -= n2; if (j >= n3) return; s = s3; d = d3; }
        }
    }
    float4 f = ((const float4*)s)[j];
    ushort4 u;
    u.x = f2bf(f.x); u.y = f2bf(f.y); u.z = f2bf(f.z); u.w = f2bf(f.w);
    ((ushort4*)d)[j] = u;
}

// ---------- wide GEMM: 128x128 tile, BK=64, XOR-swizzled LDS ----------
// lda = ldw = 2048 hardcoded. 256 threads = 4 waves (2x2); per K-iter: 8 DMA
// rounds, then 2 k-halves x (4+4 ds_read_b128 + 16 mfma). Rows are 128 B =
// 32 banks, so reads use the round-6-proven swizzle: 16B chunk c of row R at
// slot c ^ (R & 7) -> 2-way residual conflicts (free, m136).
// Epilogue splits cols: <2048 -> Xs (bf16), >=2048 -> Z (bf16).
#define WBM 128
#define WBN 128
#define WBK 64

__global__ __launch_bounds__(256) void gemm_wide(const u16* __restrict__ A,
                                                 const u16* __restrict__ W,
                                                 const float* __restrict__ bias,
                                                 u16* __restrict__ Xs,
                                                 u16* __restrict__ Z, int K) {
    __shared__ __align__(16) u16 lAB[(WBM + WBN) * WBK];  // 32 KB
    const int tid = threadIdx.x;
    const int wave = tid >> 6, lane = tid & 63;
    const int quad = lane >> 4, l16 = lane & 15;
    const int tM = blockIdx.x * WBM;
    const int tN = blockIdx.y * WBN;
    const int wr = wave >> 1, wc = wave & 1;

    // staging: 256 rows x 128B; round i covers rows i*32..i*32+31, 8 lanes/row.
    // Rounds 0-3 = A rows 0..127; 4-7 = W rows 0..127.
    const int rowin = tid >> 3;                    // 0..31
    const int col8 = ((tid & 7) ^ (rowin & 7)) * 8;  // swizzled source chunk
    const u16* gptr[8];
    u16* ldst[8];
#pragma unroll
    for (int i = 0; i < 8; ++i) {
        int trow = i * 32 + rowin;
        const u16* src = (i < 4) ? (A + (size_t)(tM + trow) * 2048)
                                 : (W + (size_t)(tN + (trow - WBM)) * 2048);
        gptr[i] = src + col8;
        ldst[i] = &lAB[(i * 32 + wave * 8) * WBK];
    }

    int a_off[2][4], b_off[2][4];
#pragma unroll
    for (int h = 0; h < 2; ++h) {
#pragma unroll
        for (int mi = 0; mi < 4; ++mi)
            a_off[h][mi] = (wr * 64 + mi * 16 + l16) * WBK +
                           (((h * 4 + quad) ^ (l16 & 7)) * 8);
#pragma unroll
        for (int ni = 0; ni < 4; ++ni)
            b_off[h][ni] = (WBM + wc * 64 + ni * 16 + l16) * WBK +
                           (((h * 4 + quad) ^ (l16 & 7)) * 8);
    }

    f32x4 acc[4][4] = {};

    for (int kt = 0; kt < K; kt += WBK) {
#pragma unroll
        for (int i = 0; i < 8; ++i) async16(gptr[i] + kt, ldst[i]);
        __syncthreads();
#pragma unroll
        for (int h = 0; h < 2; ++h) {
            bf16x8 af[4], bfr[4];
#pragma unroll
            for (int i = 0; i < 4; ++i) af[i] = *(const bf16x8*)&lAB[a_off[h][i]];
#pragma unroll
            for (int i = 0; i < 4; ++i) bfr[i] = *(const bf16x8*)&lAB[b_off[h][i]];
#pragma unroll
            for (int mi = 0; mi < 4; ++mi)
#pragma unroll
                for (int ni = 0; ni < 4; ++ni)
                    acc[mi][ni] = __builtin_amdgcn_mfma_f32_16x16x32_bf16(
                        af[mi], bfr[ni], acc[mi][ni], 0, 0, 0);
        }
        __syncthreads();
    }

    // D: row = quad*4+r, col = l16. Column range per block is uniform vs 2048.
    const bool isb_z = (tN >= 2048);
    u16* dst = isb_z ? Z : Xs;
#pragma unroll
    for (int mi = 0; mi < 4; ++mi) {
#pragma unroll
        for (int ni = 0; ni < 4; ++ni) {
            int col = tN + wc * 64 + ni * 16 + l16;
            float bv = bias[col];
            int ocol = isb_z ? (col - 2048) : col;
#pragma unroll
            for (int r = 0; r < 4; ++r) {
                int row = tM + wr * 64 + mi * 16 + quad * 4 + r;
                dst[(size_t)row * 2048 + ocol] = f2bf(acc[mi][ni][r] + bv);
            }
        }
    }
}

// ---------- narrow GEMM: BM=128, BN=64, BK=64, XOR-swizzled (round-6 form) ----------
// EPI 1 = dt: col<2048 -> min(softplus(v),1) bf16; 2048<=col<2080 -> raw dots bf16.
// EPI 2 = out: fp32 v + resid.
#define NBM 128
#define NBN 64
#define NBK 64

template <int EPI>
__global__ __launch_bounds__(256) void gemm_nw(const u16* __restrict__ A, int lda,
                                               const u16* __restrict__ W, int ldw,
                                               const float* __restrict__ bias,
                                               const float* __restrict__ resid,
                                               void* __restrict__ C, int ldc, int K,
                                               u16* __restrict__ dots) {
    __shared__ __align__(16) u16 lAB[(NBM + NBN) * NBK];  // 24 KB
    const int tid = threadIdx.x;
    const int wave = tid >> 6, lane = tid & 63;
    const int quad = lane >> 4, l16 = lane & 15;
    const int tM = blockIdx.x * NBM;
    const int tN = blockIdx.y * NBN;
    const int wr = wave >> 1, wc = wave & 1;

    const int rowin = tid >> 3;                    // 0..31
    const int r3 = rowin & 7;                      // swizzle key
    const int col8 = ((tid & 7) ^ r3) * 8;
    const u16* gptr[6];
    u16* ldst[6];
#pragma unroll
    for (int i = 0; i < 6; ++i) {
        int trow = i * 32 + rowin;
        const u16* src = (i < 4) ? (A + (size_t)(tM + trow) * lda)
                                 : (W + (size_t)(tN + (trow - NBM)) * ldw);
        gptr[i] = src + col8;
        ldst[i] = &lAB[(i * 32 + wave * 8) * NBK];
    }

    int a_off[2][4], b_off[2][2];
#pragma unroll
    for (int h = 0; h < 2; ++h) {
#pragma unroll
        for (int mi = 0; mi < 4; ++mi)
            a_off[h][mi] = (wr * 64 + mi * 16 + l16) * NBK +
                           (((h * 4 + quad) ^ (l16 & 7)) * 8);
#pragma unroll
        for (int ni = 0; ni < 2; ++ni)
            b_off[h][ni] = (NBM + wc * 32 + ni * 16 + l16) * NBK +
                           (((h * 4 + quad) ^ (l16 & 7)) * 8);
    }

    f32x4 acc[4][2] = {};

    for (int kt = 0; kt < K; kt += NBK) {
#pragma unroll
        for (int i = 0; i < 6; ++i) async16(gptr[i] + kt, ldst[i]);
        __syncthreads();
        bf16x8 af[2][4], bfr[2][2];
#pragma unroll
        for (int h = 0; h < 2; ++h) {
#pragma unroll
            for (int mi = 0; mi < 4; ++mi) af[h][mi] = *(const bf16x8*)&lAB[a_off[h][mi]];
#pragma unroll
            for (int ni = 0; ni < 2; ++ni) bfr[h][ni] = *(const bf16x8*)&lAB[b_off[h][ni]];
        }
#pragma unroll
        for (int h = 0; h < 2; ++h)
#pragma unroll
            for (int mi = 0; mi < 4; ++mi)
#pragma unroll
                for (int ni = 0; ni < 2; ++ni)
                    acc[mi][ni] = __builtin_amdgcn_mfma_f32_16x16x32_bf16(
                        af[h][mi], bfr[h][ni], acc[mi][ni], 0, 0, 0);
        __syncthreads();
    }

#pragma unroll
    for (int mi = 0; mi < 4; ++mi) {
#pragma unroll
        for (int ni = 0; ni < 2; ++ni) {
            int col = tN + wc * 32 + ni * 16 + l16;
            float bv = (EPI == 1 && col >= 2048) ? 0.f : bias[col];
#pragma unroll
            for (int r = 0; r < 4; ++r) {
                int row = tM + wr * 64 + mi * 16 + quad * 4 + r;
                float v = acc[mi][ni][r] + bv;
                if constexpr (EPI == 1) {
                    if (col < 2048) {
                        float sp = (v > 20.f) ? v : log1pf(__expf(v));
                        ((u16*)C)[(size_t)row * ldc + col] = f2bf(fminf(sp, 1.0f));
                    } else if (col < 2080) {
                        dots[(size_t)row * 32 + (col - 2048)] = f2bf(v);
                    }
                } else {
                    size_t idx = (size_t)row * ldc + col;
                    ((float*)C)[idx] = v + resid[idx];
                }
            }
        }
    }
}

// ---------- fused P + SSM + gate (split xs/z inputs) ----------
__global__ __launch_bounds__(256) void ssm_gate_kernel(const u16* __restrict__ dtb,
                                                       const u16* __restrict__ xsb,
                                                       const u16* __restrict__ zb,
                                                       const float* __restrict__ A,
                                                       const u16* __restrict__ dots,
                                                       const float* __restrict__ bB,
                                                       const float* __restrict__ bC,
                                                       u16* __restrict__ gated) {
    __shared__ float Pl[16];
    int t = blockIdx.x, tid = threadIdx.x;
    if (tid < 16) {
        float Bv = b2f(dots[(size_t)t * 32 + tid]) + bB[tid];
        float Cv = b2f(dots[(size_t)t * 32 + 16 + tid]) + bC[tid];
        Pl[tid] = Bv * Cv;
    }
    __syncthreads();
    size_t dbase = (size_t)t * DIM;
    int d0 = tid * 8;
    ushort4 dth[2], xsh[2], zh[2];
    dth[0] = *(const ushort4*)(dtb + dbase + d0);
    dth[1] = *(const ushort4*)(dtb + dbase + d0 + 4);
    xsh[0] = *(const ushort4*)(xsb + dbase + d0);
    xsh[1] = *(const ushort4*)(xsb + dbase + d0 + 4);
    zh[0]  = *(const ushort4*)(zb + dbase + d0);
    zh[1]  = *(const ushort4*)(zb + dbase + d0 + 4);
    float dtv[8], xsv[8], zv[8];
#pragma unroll
    for (int h = 0; h < 2; ++h) {
        const u16* dp = (const u16*)&dth[h];
        const u16* xp = (const u16*)&xsh[h];
        const u16* zp = (const u16*)&zh[h];
#pragma unroll
        for (int j = 0; j < 4; ++j) {
            dtv[h * 4 + j] = b2f(dp[j]);
            xsv[h * 4 + j] = b2f(xp[j]);
            zv[h * 4 + j]  = b2f(zp[j]);
        }
    }
    float s[8] = {};
#pragma unroll
    for (int n = 0; n < 16; ++n) {
        float4 a0 = *(const float4*)(A + n * DIM + d0);
        float4 a1 = *(const float4*)(A + n * DIM + d0 + 4);
        float pn = Pl[n];
        float av[8] = {a0.x, a0.y, a0.z, a0.w, a1.x, a1.y, a1.z, a1.w};
#pragma unroll
        for (int j = 0; j < 8; ++j) s[j] += pn * __expf(av[j] * dtv[j]);
    }
    ushort4 r0, r1;
    u16* rp0 = (u16*)&r0; u16* rp1 = (u16*)&r1;
#pragma unroll
    for (int j = 0; j < 8; ++j) {
        float y = s[j] * xsv[j];
        float sz = zv[j] * (1.0f / (1.0f + __expf(-zv[j])));
        u16 hv = f2bf(y * sz);
        if (j < 4) rp0[j] = hv; else rp1[j - 4] = hv;
    }
    *(ushort4*)(gated + dbase + d0) = r0;
    *(ushort4*)(gated + dbase + d0 + 4) = r1;
}

// ---------- launch ----------
// ws layout (84.15 MB peak):
//   R0 [0, 16.78M):       wb_in bf16 -> after gemm_wide: wb_out bf16 [0, 8.39M)
//   R1 [16.78M, 33.55M):  xnb bf16 -> wb_dt bf16 2112x2048 [16.78M, 25.43M)
//                         -> gated bf16 (after dt gemm, full R1)
//   R2 [33.55M, 50.33M):  xsb bf16 (T x D)
//   R3 [50.33M, 67.11M):  zb  bf16 (T x D)
//   R4 [67.11M, 83.89M):  dtb bf16 (T x D)
//   R5 [83.89M, 84.15M):  dots bf16 (T x 32)
extern "C" void kernel_launch(void* const* d_in, const int* in_sizes, int n_in,
                              void* d_out, int out_size, void* d_ws, size_t ws_size,
                              hipStream_t stream) {
    const float* x      = (const float*)d_in[0];
    const float* ln_g   = (const float*)d_in[1];
    const float* ln_b   = (const float*)d_in[2];
    const float* W_in   = (const float*)d_in[3];
    const float* b_in   = (const float*)d_in[4];
    const float* stateA = (const float*)d_in[5];
    const float* W_B    = (const float*)d_in[6];
    const float* b_B    = (const float*)d_in[7];
    const float* W_C    = (const float*)d_in[8];
    const float* b_C    = (const float*)d_in[9];
    const float* W_dt   = (const float*)d_in[10];
    const float* b_dt   = (const float*)d_in[11];
    const float* W_out  = (const float*)d_in[12];
    const float* b_out  = (const float*)d_in[13];

    char* ws = (char*)d_ws;
    u16*   wb_in  = (u16*)(ws);                     // R0
    u16*   wb_out = (u16*)(ws);                     // R0 reuse (8.4 MB)
    u16*   xnb    = (u16*)(ws + 16777216);          // R1
    u16*   wb_dt  = (u16*)(ws + 16777216);          // R1 reuse: 2112 x 2048
    u16*   gated  = (u16*)(ws + 16777216);          // R1 reuse: T x D
    u16*   xsb    = (u16*)(ws + 33554432);          // R2: T x D
    u16*   zb     = (u16*)(ws + 50331648);          // R3: T x D
    u16*   dtb    = (u16*)(ws + 67108864);          // R4: T x D
    u16*   dotsb  = (u16*)(ws + 83886080);          // R5: T x 32

    // 1. fused W_in cast + LN(x)
    castln_kernel<<<12288, 256, 0, stream>>>(W_in, wb_in, x, ln_g, ln_b, xnb);
    // 2. xz = xn @ W_in^T + b_in, split into xsb | zb   (BK=64 + swizzle)
    gemm_wide<<<dim3(32, 32), 256, 0, stream>>>(xnb, wb_in, b_in, xsb, zb, 2048);
    // 3. cast W_dt -> wb_dt rows 0..2047, W_B -> 2048..2063, W_C -> 2064..2079,
    //    W_out -> wb_out (R0). Pad rows 2080..2111 hold poison; outputs discarded.
    cast4_kernel<<<8256, 256, 0, stream>>>(
        W_dt, wb_dt, 1048576,
        W_B,  wb_dt + (size_t)2048 * 2048, 8192,
        W_C,  wb_dt + (size_t)2064 * 2048, 8192,
        W_out, wb_out, 1048576);
    // 4. dt GEMM + BC dots: narrow tiles, N = 2112 (33 tiles), 1056 blocks
    gemm_nw<1><<<dim3(32, 33), 256, 0, stream>>>(xsb, 2048, wb_dt, 2048, b_dt,
                                                 nullptr, dtb, 2048, 2048, dotsb);
    // 5. fused P + SSM + gate (gated overwrites R1; wb_dt dead)
    ssm_gate_kernel<<<T_TOK, 256, 0, stream>>>(dtb, xsb, zb, stateA, dotsb,
                                               b_B, b_C, gated);
    // 6. out = gated @ W_out^T + b_out + x, narrow tiles, 1024 blocks
    gemm_nw<2><<<dim3(32, 32), 256, 0, stream>>>(gated, 2048, wb_out, 2048, b_out,
                                                 x, (float*)d_out, 2048, 2048, nullptr);
}